// Round 2
// baseline (305.142 us; speedup 1.0000x reference)
//
#include <hip/hip_runtime.h>
#include <hip/hip_bf16.h>

typedef __bf16 bf16x8 __attribute__((ext_vector_type(8)));
typedef float  f32x4  __attribute__((ext_vector_type(4)));

#define MFMA16(A,B,C) __builtin_amdgcn_mfma_f32_16x16x32_bf16((A),(B),(C),0,0,0)

constexpr int NB = 8, NN = 8192, KK = 16;
constexpr size_t WS_NEEDED = 75776;

// ws layout (bytes):
//   w3f : [16 nb][2 ks][64 lane][8] bf16  -> 32768 B @ 0
//   w4f : [ 4 nb][8 kb][64 lane][8] bf16  -> 32768 B @ 32768
//   w2f : [ 4 nb][2 ks][64 lane][8] bf16  ->  8192 B @ 65536
//   W1f : [3][64] f32                     ->   768 B @ 73728
//   c1f : [64]  f32                       ->   256 B @ 74496
//   c3f : [256] f32                       ->  1024 B @ 74752

__global__ void prep_kernel(const float* __restrict__ W1, const float* __restrict__ b1,
                            const float* __restrict__ g1, const float* __restrict__ bt1,
                            const float* __restrict__ W2, const float* __restrict__ W3,
                            const float* __restrict__ b3, const float* __restrict__ g3,
                            const float* __restrict__ bt3, const float* __restrict__ W4,
                            unsigned char* __restrict__ ws)
{
    __bf16* w3f = (__bf16*)(ws);
    __bf16* w4f = (__bf16*)(ws + 32768);
    __bf16* w2f = (__bf16*)(ws + 65536);
    float*  W1f = (float*)(ws + 73728);
    float*  c1f = (float*)(ws + 74496);
    float*  c3f = (float*)(ws + 74752);

    const float inv = 1.0f / sqrtf(1.0f + 1e-3f);   // BN with init moving stats
    int t = blockIdx.x * 256 + threadIdx.x;

    if (t < 16384) {                    // W3 * s3 -> frag order
        int i = t & 7, lane = (t >> 3) & 63, r = t >> 9;
        int ks = r & 1, nb = r >> 1;
        int k = ks * 32 + (lane >> 4) * 8 + i;
        int n = nb * 16 + (lane & 15);
        w3f[t] = (__bf16)(W3[k * 256 + n] * (g3[n] * inv));
    } else if (t < 32768) {             // W4 / 8 -> frag order
        int u = t - 16384;
        int i = u & 7, lane = (u >> 3) & 63, r = u >> 9;
        int kb = r & 7, nb = r >> 3;
        int k = kb * 32 + (lane >> 4) * 8 + i;
        int n = nb * 16 + (lane & 15);
        w4f[u] = (__bf16)(W4[k * 64 + n] * 0.125f);
    } else if (t < 36864) {             // W2 -> frag order
        int u = t - 32768;
        int i = u & 7, lane = (u >> 3) & 63, r = u >> 9;
        int ks = r & 1, nb = r >> 1;
        int k = ks * 32 + (lane >> 4) * 8 + i;
        int n = nb * 16 + (lane & 15);
        w2f[u] = (__bf16)(W2[k * 64 + n]);
    } else if (t < 37056) {             // W1 * s1 (fp32)
        int u = t - 36864;              // u = d*64 + c
        int c = u & 63;
        W1f[u] = W1[u] * (g1[c] * inv);
    } else if (t < 37120) {             // c1f = b1*s1 + bt1
        int c = t - 37056;
        c1f[c] = b1[c] * (g1[c] * inv) + bt1[c];
    } else if (t < 37376) {             // c3f = b3*s3 + bt3
        int n = t - 37120;
        c3f[n] = b3[n] * (g3[n] * inv) + bt3[n];
    }
}

// One wave = 2 points (32 rows = 2x16 neighbor blocks). 4 waves/block, no barriers.
__global__ __launch_bounds__(256, 2) void fused_kernel(
    const float* __restrict__ key, const float* __restrict__ query,
    const float* __restrict__ value, const float* __restrict__ pos,
    const int* __restrict__ idx, const float* __restrict__ b2,
    const float* __restrict__ b4, const unsigned char* __restrict__ ws,
    float* __restrict__ out)
{
    const __bf16* w3f = (const __bf16*)(ws);
    const __bf16* w4f = (const __bf16*)(ws + 32768);
    const __bf16* w2f = (const __bf16*)(ws + 65536);
    const float*  W1f = (const float*)(ws + 73728);
    const float*  c1f = (const float*)(ws + 74496);
    const float*  c3f = (const float*)(ws + 74752);

    __shared__ __attribute__((aligned(16))) __bf16 sX [4][2048];  // h then X, swizzled
    __shared__ __attribute__((aligned(16))) __bf16 sA1[4][2048];  // GEMM1 chunk bounce
    __shared__ __attribute__((aligned(16))) float  sPR[4][32][4]; // pos_rel per row
    __shared__ int sJ[4][32];                                      // neighbor idx per row

    const int wv   = threadIdx.x >> 6;
    const int lane = threadIdx.x & 63;
    const int lg   = lane >> 4;      // 16-lane group 0..3
    const int ln   = lane & 15;

    const int ptbase = blockIdx.x * 8 + wv * 2;  // global point of rb=0
    const int b  = ptbase >> 13;                 // / 8192
    const int n0 = ptbase & 8191;

    __bf16* X  = sX[wv];
    __bf16* A1 = sA1[wv];

    // ---------- Phase A: pos_rel, neighbor idx, h = relu(pos_rel @ W1f + c1f)
    if (lane < 32) {
        int p = lane >> 4, k = lane & 15;
        int n = n0 + p;
        int j = idx[(b * NN + n) * KK + k];
        sJ[wv][lane] = j;
        int pb = (b * NN + n) * 3, jb = (b * NN + j) * 3;
        sPR[wv][lane][0] = pos[pb + 0] - pos[jb + 0];
        sPR[wv][lane][1] = pos[pb + 1] - pos[jb + 1];
        sPR[wv][lane][2] = pos[pb + 2] - pos[jb + 2];
        sPR[wv][lane][3] = 0.f;
    }
    {
        // lane = output channel c
        float w0 = W1f[lane], w1 = W1f[64 + lane], w2c = W1f[128 + lane], cc1 = c1f[lane];
        for (int r = 0; r < 32; ++r) {
            float4 pr = *(const float4*)&sPR[wv][r][0];
            float hv = fmaf(pr.x, w0, fmaf(pr.y, w1, fmaf(pr.z, w2c, cc1)));
            hv = fmaxf(hv, 0.f);
            X[(r * 64 + lane) ^ ((r & 7) << 3)] = (__bf16)hv;   // swizzled bf16 store
        }
    }

    // ---------- Phase B: pos_em = h @ W2f + b2 (kept in registers)
    bf16x8 hf[2][2];
    #pragma unroll
    for (int rb = 0; rb < 2; ++rb)
        #pragma unroll
        for (int ks = 0; ks < 2; ++ks) {
            int row = rb * 16 + ln;
            hf[rb][ks] = *(const bf16x8*)&X[(row * 64 + ks * 32 + lg * 8) ^ ((row & 7) << 3)];
        }
    f32x4 pacc[2][4];
    #pragma unroll
    for (int rb = 0; rb < 2; ++rb)
        #pragma unroll
        for (int cb = 0; cb < 4; ++cb) pacc[rb][cb] = f32x4{0.f, 0.f, 0.f, 0.f};
    #pragma unroll
    for (int cb = 0; cb < 4; ++cb)
        #pragma unroll
        for (int ks = 0; ks < 2; ++ks) {
            bf16x8 wf = *(const bf16x8*)(w2f + (size_t)((cb * 2 + ks) * 64 + lane) * 8);
            pacc[0][cb] = MFMA16(hf[0][ks], wf, pacc[0][cb]);
            pacc[1][cb] = MFMA16(hf[1][ks], wf, pacc[1][cb]);
        }

    // pos_em regs + build X = qk_rel + pos_em  (accum layout: col=ln, row=lg*4+jj)
    float posem[2][4][4];
    #pragma unroll
    for (int rb = 0; rb < 2; ++rb) {
        const int nrow = n0 + rb;
        float qv[4];
        #pragma unroll
        for (int cb = 0; cb < 4; ++cb) {
            qv[cb] = query[(b * NN + nrow) * 64 + cb * 16 + ln];
            float c2v = b2[cb * 16 + ln];
            #pragma unroll
            for (int jj = 0; jj < 4; ++jj)
                posem[rb][cb][jj] = pacc[rb][cb][jj] + c2v;
        }
        #pragma unroll
        for (int jj = 0; jj < 4; ++jj) {
            int row = rb * 16 + lg * 4 + jj;
            int jb = (b * NN + sJ[wv][row]) * 64;
            #pragma unroll
            for (int cb = 0; cb < 4; ++cb) {
                float x = qv[cb] - key[jb + cb * 16 + ln] + posem[rb][cb][jj];
                X[(row * 64 + cb * 16 + ln) ^ ((row & 7) << 3)] = (__bf16)x;
            }
        }
    }

    // ---------- Phase D: A1 = relu(X @ W3f + c3f); a2 += A1 @ W4f   (4 col-chunks)
    bf16x8 xf[2][2];
    #pragma unroll
    for (int rb = 0; rb < 2; ++rb)
        #pragma unroll
        for (int ks = 0; ks < 2; ++ks) {
            int row = rb * 16 + ln;
            xf[rb][ks] = *(const bf16x8*)&X[(row * 64 + ks * 32 + lg * 8) ^ ((row & 7) << 3)];
        }
    f32x4 acc2[2][4];
    #pragma unroll
    for (int rb = 0; rb < 2; ++rb)
        #pragma unroll
        for (int nb = 0; nb < 4; ++nb) acc2[rb][nb] = f32x4{0.f, 0.f, 0.f, 0.f};

    for (int cc = 0; cc < 4; ++cc) {
        f32x4 g1a[2][4];
        #pragma unroll
        for (int rb = 0; rb < 2; ++rb)
            #pragma unroll
            for (int cb = 0; cb < 4; ++cb) g1a[rb][cb] = f32x4{0.f, 0.f, 0.f, 0.f};
        #pragma unroll
        for (int cb = 0; cb < 4; ++cb) {
            int nb = cc * 4 + cb;
            #pragma unroll
            for (int ks = 0; ks < 2; ++ks) {
                bf16x8 wf = *(const bf16x8*)(w3f + (size_t)((nb * 2 + ks) * 64 + lane) * 8);
                g1a[0][cb] = MFMA16(xf[0][ks], wf, g1a[0][cb]);
                g1a[1][cb] = MFMA16(xf[1][ks], wf, g1a[1][cb]);
            }
        }
        // epilogue: bias+relu -> bf16 -> swizzled LDS chunk (transpose bounce)
        #pragma unroll
        for (int cb = 0; cb < 4; ++cb) {
            float c3v = c3f[(cc * 4 + cb) * 16 + ln];
            #pragma unroll
            for (int rb = 0; rb < 2; ++rb)
                #pragma unroll
                for (int jj = 0; jj < 4; ++jj) {
                    int row = rb * 16 + lg * 4 + jj;
                    float v = fmaxf(g1a[rb][cb][jj] + c3v, 0.f);
                    A1[(row * 64 + cb * 16 + ln) ^ ((row & 7) << 3)] = (__bf16)v;
                }
        }
        // GEMM2 partial over this K-chunk (64 wide)
        #pragma unroll
        for (int kb2 = 0; kb2 < 2; ++kb2) {
            bf16x8 a1f[2];
            #pragma unroll
            for (int rb = 0; rb < 2; ++rb) {
                int row = rb * 16 + ln;
                a1f[rb] = *(const bf16x8*)&A1[(row * 64 + kb2 * 32 + lg * 8) ^ ((row & 7) << 3)];
            }
            #pragma unroll
            for (int nb = 0; nb < 4; ++nb) {
                bf16x8 wf = *(const bf16x8*)(w4f + (size_t)((nb * 8 + cc * 2 + kb2) * 64 + lane) * 8);
                acc2[0][nb] = MFMA16(a1f[0], wf, acc2[0][nb]);
                acc2[1][nb] = MFMA16(a1f[1], wf, acc2[1][nb]);
            }
        }
    }

    // ---------- Phase F: channel softmax + weighted sum over K neighbors
    #pragma unroll
    for (int rb = 0; rb < 2; ++rb) {
        const int nrow = n0 + rb;
        float val[4][4];
        #pragma unroll
        for (int nb = 0; nb < 4; ++nb) {
            float b4v = b4[nb * 16 + ln] * 0.125f;
            #pragma unroll
            for (int jj = 0; jj < 4; ++jj) val[nb][jj] = acc2[rb][nb][jj] + b4v;
        }
        float vv[4];
        #pragma unroll
        for (int nb = 0; nb < 4; ++nb) vv[nb] = value[(b * NN + nrow) * 64 + nb * 16 + ln];

        float res[4] = {0.f, 0.f, 0.f, 0.f};
        #pragma unroll
        for (int jj = 0; jj < 4; ++jj) {   // each jj = one neighbor row per lane group
            float m = fmaxf(fmaxf(val[0][jj], val[1][jj]), fmaxf(val[2][jj], val[3][jj]));
            #pragma unroll
            for (int d = 1; d < 16; d <<= 1) m = fmaxf(m, __shfl_xor(m, d, 64));
            float e0 = __expf(val[0][jj] - m), e1 = __expf(val[1][jj] - m);
            float e2 = __expf(val[2][jj] - m), e3 = __expf(val[3][jj] - m);
            float s = e0 + e1 + e2 + e3;
            #pragma unroll
            for (int d = 1; d < 16; d <<= 1) s += __shfl_xor(s, d, 64);
            float inv = 1.0f / s;
            res[0] = fmaf(e0 * inv, vv[0] + posem[rb][0][jj], res[0]);
            res[1] = fmaf(e1 * inv, vv[1] + posem[rb][1][jj], res[1]);
            res[2] = fmaf(e2 * inv, vv[2] + posem[rb][2][jj], res[2]);
            res[3] = fmaf(e3 * inv, vv[3] + posem[rb][3][jj], res[3]);
        }
        #pragma unroll
        for (int nb = 0; nb < 4; ++nb) {   // sum over the 4 lane groups (16 neighbors total)
            res[nb] += __shfl_xor(res[nb], 16, 64);
            res[nb] += __shfl_xor(res[nb], 32, 64);
        }
        float o = (lg == 0) ? res[0] : (lg == 1) ? res[1] : (lg == 2) ? res[2] : res[3];
        out[(b * NN + nrow) * 64 + lane] = o;
    }
}

extern "C" void kernel_launch(void* const* d_in, const int* in_sizes, int n_in,
                              void* d_out, int out_size, void* d_ws, size_t ws_size,
                              hipStream_t stream) {
    const float* key   = (const float*)d_in[0];
    const float* query = (const float*)d_in[1];
    const float* value = (const float*)d_in[2];
    const float* pos   = (const float*)d_in[3];
    const int*   idx   = (const int*)d_in[4];
    const float* W1    = (const float*)d_in[5];
    const float* b1    = (const float*)d_in[6];
    const float* g1    = (const float*)d_in[7];
    const float* bt1   = (const float*)d_in[8];
    const float* W2    = (const float*)d_in[9];
    const float* b2    = (const float*)d_in[10];
    const float* W3    = (const float*)d_in[11];
    const float* b3    = (const float*)d_in[12];
    const float* g3    = (const float*)d_in[13];
    const float* bt3   = (const float*)d_in[14];
    const float* W4    = (const float*)d_in[15];
    const float* b4    = (const float*)d_in[16];
    unsigned char* ws  = (unsigned char*)d_ws;
    float* out = (float*)d_out;

    if (ws_size < WS_NEEDED) return;   // fail cleanly (absmax) instead of corrupting device memory

    hipLaunchKernelGGL(prep_kernel, dim3(146), dim3(256), 0, stream,
                       W1, b1, g1, bt1, W2, W3, b3, g3, bt3, W4, ws);
    hipLaunchKernelGGL(fused_kernel, dim3(8192), dim3(256), 0, stream,
                       key, query, value, pos, idx, b2, b4, ws, out);
}